// Round 2
// baseline (983.347 us; speedup 1.0000x reference)
//
#include <hip/hip_runtime.h>

typedef short bf16x8 __attribute__((ext_vector_type(8)));
typedef float f32x4  __attribute__((ext_vector_type(4)));

// Problem constants
#define NB   64
#define NT   256
#define NC   512
#define NK   1024
#define NQ   6
#define NROWS (NB*NT)        // 16384
#define QOUT_ELEMS 8388608   // B*C*T
#define IDX_ELEMS  98304     // B*T*Q
#define DELTA 0.5f           // candidate window (~10x the 512-term bf16 approx error std)

// ws layout (bytes)
#define WS_CAND   0                        // u32[16384*32] = 2 MiB
#define WS_CCNT   0x200000                 // u32[16384]
#define WS_BIDX   0x210000                 // i32[16384]
#define WS_COUNTS 0x220000                 // u32[1024]
#define WS_CSUM   0x221000                 // f32[6]
#define WS_CMEAN  0x221020                 // f32[6]
#define WS_PERP   0x221040                 // f32[6]
#define WS_DONE   0x221060                 // u32[1]
#define WS_CBN    0x222000                 // f32[6144]
#define WS_XHI    0x230000                 // ushort[16384*512], 16 MiB
#define WS_CBHI   (WS_XHI + 16777216)      // ushort[6144*512], 6 MiB

// bf16 helpers (RNE; data is gaussian, no inf/nan)
__device__ __forceinline__ unsigned short f2bf(float f) {
    unsigned u = __float_as_uint(f);
    return (unsigned short)((u + 0x7FFFu + ((u >> 16) & 1u)) >> 16);
}

__device__ __forceinline__ void load_lds16(const unsigned short* g, unsigned short* l) {
    __builtin_amdgcn_global_load_lds(
        (const __attribute__((address_space(1))) unsigned int*)g,
        (__attribute__((address_space(3))) unsigned int*)l,
        16, 0, 0);
}

// 32-bit LDS byte address for inline-asm DS ops (addrspacecast generic->local)
__device__ __forceinline__ unsigned lds_addr(const unsigned short* p) {
    return (unsigned)(unsigned long long)
        (const __attribute__((address_space(3))) unsigned short*)p;
}

// opaque ds_read_b128: compiler can't see the LDS dependency -> no auto vmcnt(0)
#define DSR(d, b, IMM) \
    asm volatile("ds_read_b128 %0, %1 offset:" #IMM : "=v"(d) : "v"(b))

// -------- codebook conversion (all 6 layers) + half-norms --------
__global__ __launch_bounds__(256) void vq_cvt_cb(const float* __restrict__ cb,
                                                 unsigned short* __restrict__ cbhi,
                                                 float* __restrict__ cbn) {
    int lane = threadIdx.x & 63, wid = threadIdx.x >> 6;
    int code = blockIdx.x * 4 + wid;                 // 0..6143
    const float* row = cb + (size_t)code * NC;
    float4 v0 = *(const float4*)(row + lane * 8);
    float4 v1 = *(const float4*)(row + lane * 8 + 4);
    float vs[8] = {v0.x, v0.y, v0.z, v0.w, v1.x, v1.y, v1.z, v1.w};
    ushort4 a, b;
    unsigned short* ap = &a.x; unsigned short* bp = &b.x;
    float s = 0.f;
    #pragma unroll
    for (int j = 0; j < 4; ++j) {
        s += vs[j] * vs[j] + vs[j+4] * vs[j+4];
        ap[j] = f2bf(vs[j]); bp[j] = f2bf(vs[j+4]);
    }
    size_t o = (size_t)code * NC + lane * 8;
    *(ushort4*)(cbhi + o) = a; *(ushort4*)(cbhi + o + 4) = b;
    #pragma unroll
    for (int off = 32; off; off >>= 1) s += __shfl_down(s, off, 64);
    if (lane == 0) cbn[code] = 0.5f * s;
}

// -------- x conversion: (B,C,T) fp32 -> (r=b*T+t, c) bf16; also zero flags ----
__global__ __launch_bounds__(256) void vq_cvt_x(const float* __restrict__ x,
                                                unsigned short* __restrict__ xh,
                                                unsigned int* __restrict__ candcnt,
                                                unsigned int* __restrict__ done) {
    __shared__ unsigned short hs[64][72];
    int bx = blockIdx.x;
    int b = bx >> 5, tt = (bx >> 3) & 3, c0 = (bx & 7) << 6;
    int t0 = tt << 6, tid = threadIdx.x;
    if ((bx & 7) == 0 && tid < 64) candcnt[b * 256 + t0 + tid] = 0u;  // layer-0 init
    if (bx == 0 && tid == 0) *done = 0u;
    const float* base = x + (size_t)b * (NC * NT) + t0;
    #pragma unroll
    for (int i = 0; i < 4; ++i) {
        int f = tid + (i << 8);
        int c_l = f >> 4, t4 = f & 15;
        float4 v = *(const float4*)(base + (size_t)(c0 + c_l) * NT + (t4 << 2));
        ushort4 hh;
        hh.x = f2bf(v.x); hh.y = f2bf(v.y); hh.z = f2bf(v.z); hh.w = f2bf(v.w);
        *(ushort4*)&hs[c_l][t4 << 2] = hh;
    }
    __syncthreads();
    int row0 = b * NT + t0;
    #pragma unroll
    for (int i = 0; i < 4; ++i) {
        int f = tid + (i << 8);
        int r_l = f >> 4, c4 = f & 15;
        ushort4 hh;
        hh.x = hs[c4*4+0][r_l]; hh.y = hs[c4*4+1][r_l];
        hh.z = hs[c4*4+2][r_l]; hh.w = hs[c4*4+3][r_l];
        *(ushort4*)(xh + (size_t)(row0 + r_l) * NC + c0 + (c4 << 2)) = hh;
    }
}

// -------- bf16 MFMA approx distance + candidate emission --------
// 256x256 tile, 512 threads = 8 waves (2M x 4N), BK=64, double-buffered LDS.
// ALL inner-loop LDS reads are inline-asm ds_read_b128 on precomputed 32-bit
// LDS addresses, so the compiler's waitcnt pass cannot see an aliasing
// dependency on the outstanding global_load_lds ops -> the ONLY vmem waits in
// the loop are our counted vmcnt(8); next-tile loads stay in flight across
// both barriers (T3+T4 counted-vmcnt pipeline).
// XOR-swizzled LDS: chunk (16B) of row r stored at slot q^(r&7)
// -> conflict-free ds_read_b128 AND legal global_load_lds dest (base+lane*16).
__global__ __launch_bounds__(512, 2) void vq_dist(
    const unsigned short* __restrict__ xh, const unsigned short* __restrict__ ch,
    const float* __restrict__ cbn,
    unsigned int* __restrict__ cand, unsigned int* __restrict__ candcnt,
    unsigned int* __restrict__ counts, float* __restrict__ commit_slot)
{
    extern __shared__ unsigned short smem[];   // 2 bufs x (A 16384 + B 16384 ushorts) = 128 KiB
    const int rb = blockIdx.x, cg = blockIdx.y, tid = threadIdx.x;
    if (rb == 0 && cg == 0) {     // init for rescore/update of this layer
        for (int i = tid; i < NK; i += 512) counts[i] = 0u;
        if (tid == 0) *commit_slot = 0.f;
    }
    const int wave = tid >> 6, lane = tid & 63;
    const int idx16 = lane & 15, quad = lane >> 4;
    const int wm = wave >> 2, wn = wave & 3;
    const int m0 = rb * 256, n0 = cg * 256;

    // staging: waves 0-3 -> A (xh rows m0..m0+255), waves 4-7 -> B (ch rows n0..n0+255)
    const unsigned short* gsrc = (wave < 4) ? xh : ch;
    const int rbase = (wave < 4) ? m0 : n0;
    const int wrow  = ((wave & 3) << 6) + (lane >> 3);      // row in 256-tile (+8 per instr i)
    const int sq    = (lane & 7) ^ ((lane >> 3) & 7);       // pre-swizzled source chunk
    const unsigned short* gp = gsrc + (size_t)(rbase + wrow) * NC + sq * 8;
    unsigned short* lp0 = &smem[((wave < 4) ? 0 : 16384) + ((wave & 3) << 12) + lane * 8];

    // per-wave LDS read base addresses [buf][ks]; mt/nt walk via offset: immediates
    const int r7 = idx16 & 7;
    unsigned aB[2][2], bB[2][2];
    #pragma unroll
    for (int ks = 0; ks < 2; ++ks) {
        int slot = ((quad + 4 * ks) ^ r7) << 3;             // ushort units
        aB[0][ks] = lds_addr(&smem[(wm * 128 + idx16) * 64 + slot]);
        bB[0][ks] = lds_addr(&smem[16384 + (wn * 64 + idx16) * 64 + slot]);
        aB[1][ks] = aB[0][ks] + 65536u;
        bB[1][ks] = bB[0][ks] + 65536u;
    }

    f32x4 acc[8][4];
    #pragma unroll
    for (int mt = 0; mt < 8; ++mt)
        #pragma unroll
        for (int nt = 0; nt < 4; ++nt) acc[mt][nt] = (f32x4){0.f, 0.f, 0.f, 0.f};

    // prologue: stage K-step 0 into buffer 0
    #pragma unroll
    for (int i = 0; i < 8; ++i)
        load_lds16(gp + (size_t)(i * 8) * NC, lp0 + i * 512);

    #define KS_BODY(ABASE, BBASE)                                              \
    {                                                                          \
        bf16x8 a[8], b[4];                                                     \
        DSR(a[0], ABASE, 0);     DSR(a[1], ABASE, 2048);                       \
        DSR(a[2], ABASE, 4096);  DSR(a[3], ABASE, 6144);                       \
        DSR(a[4], ABASE, 8192);  DSR(a[5], ABASE, 10240);                      \
        DSR(a[6], ABASE, 12288); DSR(a[7], ABASE, 14336);                      \
        DSR(b[0], BBASE, 0);     DSR(b[1], BBASE, 2048);                       \
        DSR(b[2], BBASE, 4096);  DSR(b[3], BBASE, 6144);                       \
        asm volatile("s_waitcnt lgkmcnt(0)" ::: "memory");                     \
        __builtin_amdgcn_sched_barrier(0);                                     \
        __builtin_amdgcn_s_setprio(1);                                         \
        _Pragma("unroll")                                                      \
        for (int mt = 0; mt < 8; ++mt)                                         \
            _Pragma("unroll")                                                  \
            for (int nt = 0; nt < 4; ++nt)                                     \
                acc[mt][nt] = __builtin_amdgcn_mfma_f32_16x16x32_bf16(         \
                    a[mt], b[nt], acc[mt][nt], 0, 0, 0);                       \
        __builtin_amdgcn_s_setprio(0);                                         \
        __builtin_amdgcn_sched_barrier(0);                                     \
    }

    #pragma unroll
    for (int k = 0; k < 8; ++k) {
        const int BUF = k & 1;
        if (k < 7) {
            // issue next K-step's loads into the other buffer; keep them in flight
            unsigned short* lp = lp0 + ((BUF ^ 1) << 15);
            const unsigned short* g = gp + (k + 1) * 64;
            #pragma unroll
            for (int i = 0; i < 8; ++i)
                load_lds16(g + (size_t)(i * 8) * NC, lp + i * 512);
            asm volatile("s_waitcnt vmcnt(8)" ::: "memory");   // current buffer ready
        } else {
            asm volatile("s_waitcnt vmcnt(0)" ::: "memory");
        }
        __builtin_amdgcn_s_barrier();
        __builtin_amdgcn_sched_barrier(0);
        KS_BODY(aB[BUF][0], bB[BUF][0]);
        KS_BODY(aB[BUF][1], bB[BUF][1]);
        __builtin_amdgcn_s_barrier();
        __builtin_amdgcn_sched_barrier(0);
    }
    #undef KS_BODY

    // epilogue: per-row wave-min over this wave's 64 codes, delta-window emission
    float cn[4]; int ng[4];
    #pragma unroll
    for (int nt = 0; nt < 4; ++nt) {
        ng[nt] = n0 + wn * 64 + nt * 16 + idx16;
        cn[nt] = cbn[ng[nt]];
    }
    #pragma unroll
    for (int mt = 0; mt < 8; ++mt) {
        #pragma unroll
        for (int r = 0; r < 4; ++r) {
            float sc[4];
            float m = 3.402823466e38f;
            #pragma unroll
            for (int nt = 0; nt < 4; ++nt) {
                sc[nt] = cn[nt] - acc[mt][nt][r];
                m = fminf(m, sc[nt]);
            }
            #pragma unroll
            for (int sft = 1; sft < 16; sft <<= 1)
                m = fminf(m, __shfl_xor(m, sft, 64));
            m += DELTA;
            const int row = m0 + wm * 128 + mt * 16 + quad * 4 + r;
            #pragma unroll
            for (int nt = 0; nt < 4; ++nt) {
                if (sc[nt] <= m) {
                    unsigned slot = atomicAdd(&candcnt[row], 1u);
                    if (slot < 32u) cand[(size_t)row * 32 + slot] = (unsigned)ng[nt];
                }
            }
        }
    }
}

// -------- exact fp32 rescore of candidates: final argmin + histogram --------
// grid 1024 blocks (16 rows each), 256 threads = 4 waves, 4 rows/wave.
__global__ __launch_bounds__(256) void vq_rescore(
    const float* __restrict__ src,     // residual (B,C,T) current layer input
    const float* __restrict__ cb, const float* __restrict__ cbn,
    const unsigned int* __restrict__ cand, const unsigned int* __restrict__ candcnt,
    int* __restrict__ best_idx, float* __restrict__ out_idx,
    unsigned int* __restrict__ counts, int q)
{
    __shared__ float xl[16][512];      // [t_local][c], 32 KiB
    const int tid = threadIdx.x;
    const int b = blockIdx.x >> 4, t0 = (blockIdx.x & 15) << 4;
    const float* base = src + (size_t)b * (NC * NT) + t0;
    #pragma unroll
    for (int i = 0; i < 8; ++i) {
        int f = tid + (i << 8);
        int c = f >> 2, t4 = f & 3;
        float4 v = *(const float4*)(base + (size_t)c * NT + (t4 << 2));
        xl[(t4 << 2) + 0][c] = v.x; xl[(t4 << 2) + 1][c] = v.y;
        xl[(t4 << 2) + 2][c] = v.z; xl[(t4 << 2) + 3][c] = v.w;
    }
    __syncthreads();
    const int w = tid >> 6, lane = tid & 63;
    const int row0 = b * NT + t0;
    for (int rr = 0; rr < 4; ++rr) {
        const int tl = w * 4 + rr;
        const int row = row0 + tl;
        float4 xa = *(const float4*)&xl[tl][lane << 3];
        float4 xb = *(const float4*)&xl[tl][(lane << 3) + 4];
        int n = (int)candcnt[row]; if (n > 32) n = 32;
        float bs = 3.402823466e38f; int bi = 0x7FFFFFFF;
        for (int j = 0; j < n; ++j) {
            int code = (int)cand[(size_t)row * 32 + j];
            const float* cr = cb + (size_t)code * NC + (lane << 3);
            float4 ca = *(const float4*)cr;
            float4 cc = *(const float4*)(cr + 4);
            float s = xa.x*ca.x + xa.y*ca.y + xa.z*ca.z + xa.w*ca.w
                    + xb.x*cc.x + xb.y*cc.y + xb.z*cc.z + xb.w*cc.w;
            #pragma unroll
            for (int off = 1; off < 64; off <<= 1) s += __shfl_xor(s, off, 64);
            s = cbn[code] - s;
            if (s < bs || (s == bs && code < bi)) { bs = s; bi = code; }
        }
        if (lane == 0) {
            best_idx[row] = bi;
            out_idx[(size_t)row * NQ + q] = (float)bi;
            atomicAdd(&counts[bi], 1u);
        }
    }
}

// -------- gather + residual update + commit + bf16 emit + FUSED stats --------
// grid 256 blocks (64 rows each), 256 threads; last block computes perp/cmean.
__global__ __launch_bounds__(256) void vq_update(
    const float* __restrict__ src,    // residual before (x for q=0), (B,C,T)
    float* __restrict__ dst,          // residual after (d_out qout slot)
    const float* __restrict__ cb,
    const int* __restrict__ best_idx,
    unsigned short* __restrict__ xh,  // bf16 residual for next layer's dist
    unsigned int* __restrict__ candcnt,
    unsigned int* __restrict__ counts,
    float* __restrict__ csum, float* __restrict__ cmean, float* __restrict__ perp,
    float* __restrict__ out_tail, unsigned int* __restrict__ done, int q)
{
    const int rb = blockIdx.x, tid = threadIdx.x;
    const int b = rb >> 2, t0 = (rb & 3) << 6;
    const int row0 = rb * 64;                    // = b*256 + t0
    __shared__ int s_idx[64];
    __shared__ __align__(16) float qt[64][68];   // [c_local][t_local]
    __shared__ float wsum[4];
    __shared__ unsigned int lastflag;
    if (tid < 64) {
        s_idx[tid] = best_idx[row0 + tid];
        candcnt[row0 + tid] = 0u;                // reset for next layer's dist
    }
    __syncthreads();
    float cs = 0.f;
    const size_t base = (size_t)b * (NC * NT) + t0;
    for (int ct = 0; ct < 8; ++ct) {             // c chunks of 64
        if (ct) __syncthreads();
        // gather cb[idx[r]] chunk into qt [c][t]
        #pragma unroll
        for (int i = 0; i < 4; ++i) {
            int f = tid + (i << 8);
            int r = f >> 4, cf = f & 15;
            float4 v = *(const float4*)(cb + (size_t)s_idx[r] * NC + ct * 64 + (cf << 2));
            qt[(cf << 2) + 0][r] = v.x;
            qt[(cf << 2) + 1][r] = v.y;
            qt[(cf << 2) + 2][r] = v.z;
            qt[(cf << 2) + 3][r] = v.w;
        }
        __syncthreads();
        // residual RMW (coalesced along t); overwrite qt cells with n in place
        #pragma unroll
        for (int i = 0; i < 4; ++i) {
            int f = tid + (i << 8);
            int c_l = f >> 4, tf = f & 15;
            size_t o = base + (size_t)(ct * 64 + c_l) * NT + (tf << 2);
            float4 r4 = *(const float4*)(src + o);
            float4 q4 = *(const float4*)&qt[c_l][tf << 2];
            float4 n;
            n.x = r4.x - q4.x; n.y = r4.y - q4.y; n.z = r4.z - q4.z; n.w = r4.w - q4.w;
            *(float4*)(dst + o) = n;
            *(float4*)&qt[c_l][tf << 2] = n;
            cs += n.x*n.x + n.y*n.y + n.z*n.z + n.w*n.w;
        }
        __syncthreads();
        // transpose-read n and emit bf16 in (r,c) layout
        #pragma unroll
        for (int i = 0; i < 4; ++i) {
            int f = tid + (i << 8);
            int r_l = f >> 4, c4 = f & 15;
            ushort4 hh;
            hh.x = f2bf(qt[c4*4+0][r_l]); hh.y = f2bf(qt[c4*4+1][r_l]);
            hh.z = f2bf(qt[c4*4+2][r_l]); hh.w = f2bf(qt[c4*4+3][r_l]);
            *(ushort4*)(xh + (size_t)(row0 + r_l) * NC + ct * 64 + (c4 << 2)) = hh;
        }
    }
    #pragma unroll
    for (int off = 32; off; off >>= 1) cs += __shfl_down(cs, off, 64);
    if ((tid & 63) == 0) wsum[tid >> 6] = cs;
    __syncthreads();
    if (tid == 0) {
        atomicAdd(&csum[q], wsum[0] + wsum[1] + wsum[2] + wsum[3]);
        __threadfence();
        lastflag = atomicAdd(done, 1u);
    }
    __syncthreads();
    if (lastflag == 255u) {                      // last block: fused per-layer stats
        float v = 0.f;
        for (int i = tid; i < NK; i += 256) {
            float p = (float)atomicAdd(&counts[i], 0u) * (1.f / (float)NROWS);
            v += p * logf(p + 1e-7f);
        }
        #pragma unroll
        for (int off = 32; off; off >>= 1) v += __shfl_down(v, off, 64);
        if ((tid & 63) == 0) wsum[tid >> 6] = v;
        __syncthreads();
        if (tid == 0) {
            float S = wsum[0] + wsum[1] + wsum[2] + wsum[3];
            perp[q]  = expf(-S);
            cmean[q] = atomicAdd(&csum[q], 0.f) * (1.f / ((float)NROWS * (float)NC));
            if (q == NQ - 1) {
                float mc = 0.f, mp = 0.f;
                for (int i = 0; i < NQ; ++i) { mc += cmean[i]; mp += perp[i]; }
                out_tail[0] = mc / (float)NQ;
                out_tail[1] = mp / (float)NQ;
            }
            *done = 0u;                          // reset for next layer
        }
    }
}

// -------- qout = x - residual_final (elementwise, in place) --------
__global__ void vq_finalize(const float* __restrict__ x, float* __restrict__ res, int n4) {
    int i = blockIdx.x * blockDim.x + threadIdx.x;
    if (i < n4) {
        float4 a = ((const float4*)x)[i];
        float4 r = ((float4*)res)[i];
        float4 o;
        o.x = a.x - r.x; o.y = a.y - r.y; o.z = a.z - r.z; o.w = a.w - r.w;
        ((float4*)res)[i] = o;
    }
}

extern "C" void kernel_launch(void* const* d_in, const int* in_sizes, int n_in,
                              void* d_out, int out_size, void* d_ws, size_t ws_size,
                              hipStream_t stream) {
    static int inited = 0;
    if (!inited) {
        // allow 128 KiB dynamic LDS for vq_dist (gfx950 has 160 KiB/CU)
        (void)hipFuncSetAttribute((const void*)vq_dist,
                                  hipFuncAttributeMaxDynamicSharedMemorySize, 131072);
        inited = 1;
    }
    const float* x  = (const float*)d_in[0];
    const float* cb = (const float*)d_in[1];       // (Q,K,C)
    float* out      = (float*)d_out;
    float* res      = out;                          // residual lives in qout slot
    float* out_idx  = out + QOUT_ELEMS;
    float* out_tail = out + QOUT_ELEMS + IDX_ELEMS;
    char* ws = (char*)d_ws;
    unsigned int* cand    = (unsigned int*)(ws + WS_CAND);
    unsigned int* candcnt = (unsigned int*)(ws + WS_CCNT);
    int*          bidx    = (int*)(ws + WS_BIDX);
    unsigned int* counts  = (unsigned int*)(ws + WS_COUNTS);
    float* csum  = (float*)(ws + WS_CSUM);
    float* cmean = (float*)(ws + WS_CMEAN);
    float* perp  = (float*)(ws + WS_PERP);
    unsigned int* done = (unsigned int*)(ws + WS_DONE);
    float* cbn   = (float*)(ws + WS_CBN);
    unsigned short* xh   = (unsigned short*)(ws + WS_XHI);
    unsigned short* cbhi = (unsigned short*)(ws + WS_CBHI);

    vq_cvt_cb<<<1536, 256, 0, stream>>>(cb, cbhi, cbn);
    vq_cvt_x<<<2048, 256, 0, stream>>>(x, xh, candcnt, done);
    for (int q = 0; q < NQ; ++q) {
        const float* src = (q == 0) ? x : res;
        const float* cbq = cb + (size_t)q * NK * NC;
        vq_dist<<<dim3(64, 4), 512, 131072, stream>>>(
            xh, cbhi + (size_t)q * NK * NC, cbn + q * NK,
            cand, candcnt, counts, csum + q);
        vq_rescore<<<1024, 256, 0, stream>>>(src, cbq, cbn + q * NK, cand, candcnt,
                                             bidx, out_idx, counts, q);
        vq_update<<<256, 256, 0, stream>>>(src, res, cbq, bidx, xh, candcnt,
                                           counts, csum, cmean, perp, out_tail, done, q);
    }
    vq_finalize<<<8192, 256, 0, stream>>>(x, res, QOUT_ELEMS / 4);
}

// Round 3
// 761.559 us; speedup vs baseline: 1.2912x; 1.2912x over previous
//
#include <hip/hip_runtime.h>

typedef short bf16x8 __attribute__((ext_vector_type(8)));
typedef float f32x4  __attribute__((ext_vector_type(4)));

// Problem constants
#define NB   64
#define NT   256
#define NC   512
#define NK   1024
#define NQ   6
#define NROWS (NB*NT)        // 16384
#define QOUT_ELEMS 8388608   // B*C*T
#define IDX_ELEMS  98304     // B*T*Q
#define DELTA 0.5f           // candidate window (~10x the 512-term bf16 approx error std)
#define CAP  64              // candidate slots per row (uint2 pairs)

// ws layout (bytes)
#define WS_CAND   0                        // uint2[16384*64] = 8 MiB
#define WS_CCNT   0x800000                 // u32[16384]
#define WS_BIDX   0x810000                 // i32[16384]
#define WS_COUNTS 0x820000                 // u32[1024]
#define WS_CSUM   0x821000                 // f32[6]
#define WS_CMEAN  0x821020                 // f32[6]
#define WS_PERP   0x821040                 // f32[6]
#define WS_DONE   0x821060                 // u32[1]
#define WS_CBN    0x822000                 // f32[6144]
#define WS_XHI    0x830000                 // ushort[8 panels][16384][64], 16 MiB (panel-major)
#define WS_CBHI   (WS_XHI + 16777216)      // ushort[6 layers][8 panels][1024][64], 6 MiB

// bf16 helpers (RNE; data is gaussian, no inf/nan)
__device__ __forceinline__ unsigned short f2bf(float f) {
    unsigned u = __float_as_uint(f);
    return (unsigned short)((u + 0x7FFFu + ((u >> 16) & 1u)) >> 16);
}

__device__ __forceinline__ void load_lds16(const unsigned short* g, unsigned short* l) {
    __builtin_amdgcn_global_load_lds(
        (const __attribute__((address_space(1))) unsigned int*)g,
        (__attribute__((address_space(3))) unsigned int*)l,
        16, 0, 0);
}

// 32-bit LDS byte address for inline-asm DS ops (addrspacecast generic->local)
__device__ __forceinline__ unsigned lds_addr(const unsigned short* p) {
    return (unsigned)(unsigned long long)
        (const __attribute__((address_space(3))) unsigned short*)p;
}

// opaque ds_read_b128: compiler can't see the LDS dependency -> no auto vmcnt(0)
#define DSR(d, b, IMM) \
    asm volatile("ds_read_b128 %0, %1 offset:" #IMM : "=v"(d) : "v"(b))

// -------- codebook conversion (all 6 layers) + half-norms --------
// Emits PANEL-MAJOR swizzled layout: per layer [kk=0..7][code][8 chunks of 16B],
// chunk cq of row stored at slot cq^(code&7) (bank-conflict-free ds_read later).
__global__ __launch_bounds__(256) void vq_cvt_cb(const float* __restrict__ cb,
                                                 unsigned short* __restrict__ cbhi,
                                                 float* __restrict__ cbn) {
    int lane = threadIdx.x & 63, wid = threadIdx.x >> 6;
    int code = blockIdx.x * 4 + wid;                 // 0..6143
    int layer = code >> 10, cin = code & 1023;
    const float* row = cb + (size_t)code * NC;
    float4 v0 = *(const float4*)(row + lane * 8);
    float4 v1 = *(const float4*)(row + lane * 8 + 4);
    float vs[8] = {v0.x, v0.y, v0.z, v0.w, v1.x, v1.y, v1.z, v1.w};
    ushort4 a, b;
    unsigned short* ap = &a.x; unsigned short* bp = &b.x;
    float s = 0.f;
    #pragma unroll
    for (int j = 0; j < 4; ++j) {
        s += vs[j] * vs[j] + vs[j+4] * vs[j+4];
        ap[j] = f2bf(vs[j]); bp[j] = f2bf(vs[j+4]);
    }
    // lane covers dims lane*8..lane*8+7 = panel kk=lane>>3, chunk cq=lane&7
    size_t o = (size_t)layer * NK * NC
             + (((size_t)(lane >> 3) * NK + cin) << 6)
             + (((lane & 7) ^ (cin & 7)) << 3);
    *(ushort4*)(cbhi + o) = a; *(ushort4*)(cbhi + o + 4) = b;
    #pragma unroll
    for (int off = 32; off; off >>= 1) s += __shfl_down(s, off, 64);
    if (lane == 0) cbn[code] = 0.5f * s;
}

// -------- x conversion: (B,C,T) fp32 -> panel-major swizzled bf16 ----
__global__ __launch_bounds__(256) void vq_cvt_x(const float* __restrict__ x,
                                                unsigned short* __restrict__ xh,
                                                unsigned int* __restrict__ candcnt,
                                                unsigned int* __restrict__ done) {
    __shared__ unsigned short hs[64][72];
    int bx = blockIdx.x;
    int b = bx >> 5, tt = (bx >> 3) & 3, kk = bx & 7;   // kk = panel (64-dim chunk)
    int c0 = kk << 6, t0 = tt << 6, tid = threadIdx.x;
    if (kk == 0 && tid < 64) candcnt[b * 256 + t0 + tid] = 0u;  // layer-0 init
    if (bx == 0 && tid == 0) *done = 0u;
    const float* base = x + (size_t)b * (NC * NT) + t0;
    #pragma unroll
    for (int i = 0; i < 4; ++i) {
        int f = tid + (i << 8);
        int c_l = f >> 4, t4 = f & 15;
        float4 v = *(const float4*)(base + (size_t)(c0 + c_l) * NT + (t4 << 2));
        ushort4 hh;
        hh.x = f2bf(v.x); hh.y = f2bf(v.y); hh.z = f2bf(v.z); hh.w = f2bf(v.w);
        *(ushort4*)&hs[c_l][t4 << 2] = hh;
    }
    __syncthreads();
    int row0 = b * NT + t0;
    #pragma unroll
    for (int i = 0; i < 4; ++i) {
        int f = tid + (i << 8);
        int r_l = f >> 4, c4 = f & 15;
        ushort4 hh;
        hh.x = hs[c4*4+0][r_l]; hh.y = hs[c4*4+1][r_l];
        hh.z = hs[c4*4+2][r_l]; hh.w = hs[c4*4+3][r_l];
        int cq = c4 >> 1, h = c4 & 1;
        *(ushort4*)(xh + (((size_t)kk * NROWS + row0 + r_l) << 6)
                       + ((cq ^ (r_l & 7)) << 3) + (h << 2)) = hh;
    }
}

// -------- bf16 MFMA approx distance + (code,score) candidate emission --------
// 256x256 tile, 512 threads = 8 waves (2M x 4N), BK=64, double-buffered LDS,
// counted vmcnt(8) + raw barriers. Sources are PANEL-MAJOR: every
// global_load_lds wave-op is one fully CONTIGUOUS 1 KiB burst (source chunks
// pre-swizzled at emission so LDS dest stays linear & ds_read conflict-free).
__global__ __launch_bounds__(512, 2) void vq_dist(
    const unsigned short* __restrict__ xh, const unsigned short* __restrict__ ch,
    const float* __restrict__ cbn,
    unsigned int* __restrict__ cand, unsigned int* __restrict__ candcnt,
    unsigned int* __restrict__ counts, float* __restrict__ commit_slot)
{
    extern __shared__ unsigned short smem[];   // 2 bufs x (A 16384 + B 16384 ushorts) = 128 KiB
    const int rb = blockIdx.x, cg = blockIdx.y, tid = threadIdx.x;
    if (rb == 0 && cg == 0) {     // init for rescore/update of this layer
        for (int i = tid; i < NK; i += 512) counts[i] = 0u;
        if (tid == 0) *commit_slot = 0.f;
    }
    const int wave = tid >> 6, lane = tid & 63;
    const int idx16 = lane & 15, quad = lane >> 4;
    const int wm = wave >> 2, wn = wave & 3;
    const int m0 = rb * 256, n0 = cg * 256;

    // staging: waves 0-3 -> A (xh panel rows m0..), waves 4-7 -> B (ch panel rows n0..)
    const unsigned short* gsrc = (wave < 4) ? xh : ch;
    const int tbase = (wave < 4) ? m0 : n0;
    const size_t strideK = (size_t)((wave < 4) ? NROWS : NK) << 6;   // ushorts per K-step
    const unsigned short* gp = gsrc + ((size_t)tbase << 6) + ((wave & 3) << 12) + lane * 8;
    unsigned short* lp0 = &smem[((wave < 4) ? 0 : 16384) + ((wave & 3) << 12) + lane * 8];

    // per-wave LDS read base addresses [buf][ks]; mt/nt walk via offset: immediates
    unsigned aB[2][2], bB[2][2];
    #pragma unroll
    for (int ks = 0; ks < 2; ++ks) {
        int slot = ((quad + 4 * ks) ^ (idx16 & 7)) << 3;            // ushort units
        aB[0][ks] = lds_addr(&smem[(wm * 128 + idx16) * 64 + slot]);
        bB[0][ks] = lds_addr(&smem[16384 + (wn * 64 + idx16) * 64 + slot]);
        aB[1][ks] = aB[0][ks] + 65536u;
        bB[1][ks] = bB[0][ks] + 65536u;
    }

    f32x4 acc[8][4];
    #pragma unroll
    for (int mt = 0; mt < 8; ++mt)
        #pragma unroll
        for (int nt = 0; nt < 4; ++nt) acc[mt][nt] = (f32x4){0.f, 0.f, 0.f, 0.f};

    // prologue: stage K-step 0 into buffer 0 (contiguous 8 KiB per wave)
    #pragma unroll
    for (int i = 0; i < 8; ++i)
        load_lds16(gp + i * 512, lp0 + i * 512);

    #define KS_BODY(ABASE, BBASE)                                              \
    {                                                                          \
        bf16x8 a[8], b[4];                                                     \
        DSR(a[0], ABASE, 0);     DSR(a[1], ABASE, 2048);                       \
        DSR(a[2], ABASE, 4096);  DSR(a[3], ABASE, 6144);                       \
        DSR(a[4], ABASE, 8192);  DSR(a[5], ABASE, 10240);                      \
        DSR(a[6], ABASE, 12288); DSR(a[7], ABASE, 14336);                      \
        DSR(b[0], BBASE, 0);     DSR(b[1], BBASE, 2048);                       \
        DSR(b[2], BBASE, 4096);  DSR(b[3], BBASE, 6144);                       \
        asm volatile("s_waitcnt lgkmcnt(0)" ::: "memory");                     \
        __builtin_amdgcn_sched_barrier(0);                                     \
        __builtin_amdgcn_s_setprio(1);                                         \
        _Pragma("unroll")                                                      \
        for (int mt = 0; mt < 8; ++mt)                                         \
            _Pragma("unroll")                                                  \
            for (int nt = 0; nt < 4; ++nt)                                     \
                acc[mt][nt] = __builtin_amdgcn_mfma_f32_16x16x32_bf16(         \
                    a[mt], b[nt], acc[mt][nt], 0, 0, 0);                       \
        __builtin_amdgcn_s_setprio(0);                                         \
        __builtin_amdgcn_sched_barrier(0);                                     \
    }

    #pragma unroll
    for (int k = 0; k < 8; ++k) {
        const int BUF = k & 1;
        if (k < 7) {
            // issue next K-step's loads into the other buffer; keep them in flight
            unsigned short* lp = lp0 + ((BUF ^ 1) << 15);
            const unsigned short* g = gp + (size_t)(k + 1) * strideK;
            #pragma unroll
            for (int i = 0; i < 8; ++i)
                load_lds16(g + i * 512, lp + i * 512);
            asm volatile("s_waitcnt vmcnt(8)" ::: "memory");   // current buffer ready
        } else {
            asm volatile("s_waitcnt vmcnt(0)" ::: "memory");
        }
        __builtin_amdgcn_s_barrier();
        __builtin_amdgcn_sched_barrier(0);
        KS_BODY(aB[BUF][0], bB[BUF][0]);
        KS_BODY(aB[BUF][1], bB[BUF][1]);
        __builtin_amdgcn_s_barrier();
        __builtin_amdgcn_sched_barrier(0);
    }
    #undef KS_BODY

    // epilogue: per-row wave-min over this wave's 64 codes, delta-window emission
    float cn[4]; int ng[4];
    #pragma unroll
    for (int nt = 0; nt < 4; ++nt) {
        ng[nt] = n0 + wn * 64 + nt * 16 + idx16;
        cn[nt] = cbn[ng[nt]];
    }
    #pragma unroll
    for (int mt = 0; mt < 8; ++mt) {
        #pragma unroll
        for (int r = 0; r < 4; ++r) {
            float sc[4];
            float m = 3.402823466e38f;
            #pragma unroll
            for (int nt = 0; nt < 4; ++nt) {
                sc[nt] = cn[nt] - acc[mt][nt][r];
                m = fminf(m, sc[nt]);
            }
            #pragma unroll
            for (int sft = 1; sft < 16; sft <<= 1)
                m = fminf(m, __shfl_xor(m, sft, 64));
            m += DELTA;
            const int row = m0 + wm * 128 + mt * 16 + quad * 4 + r;
            #pragma unroll
            for (int nt = 0; nt < 4; ++nt) {
                if (sc[nt] <= m) {
                    unsigned slot = atomicAdd(&candcnt[row], 1u);
                    if (slot < (unsigned)CAP)
                        ((uint2*)cand)[(size_t)row * CAP + slot] =
                            make_uint2((unsigned)ng[nt], __float_as_uint(sc[nt]));
                }
            }
        }
    }
}

// -------- exact fp32 rescore: global-min filter, then argmin + histogram ----
// grid 1024 blocks (16 rows each), 256 threads = 4 waves, 4 rows/wave.
// Lane-parallel pair scan -> row min of approx scores -> dot ONLY candidates
// within min+DELTA (~1.3/row instead of ~18).
__global__ __launch_bounds__(256) void vq_rescore(
    const float* __restrict__ src,     // residual (B,C,T) current layer input
    const float* __restrict__ cb, const float* __restrict__ cbn,
    const unsigned int* __restrict__ cand, const unsigned int* __restrict__ candcnt,
    int* __restrict__ best_idx, float* __restrict__ out_idx,
    unsigned int* __restrict__ counts, int q)
{
    __shared__ float xl[16][512];      // [t_local][c], 32 KiB
    const int tid = threadIdx.x;
    const int b = blockIdx.x >> 4, t0 = (blockIdx.x & 15) << 4;
    const float* base = src + (size_t)b * (NC * NT) + t0;
    #pragma unroll
    for (int i = 0; i < 8; ++i) {
        int f = tid + (i << 8);
        int c = f >> 2, t4 = f & 3;
        float4 v = *(const float4*)(base + (size_t)c * NT + (t4 << 2));
        xl[(t4 << 2) + 0][c] = v.x; xl[(t4 << 2) + 1][c] = v.y;
        xl[(t4 << 2) + 2][c] = v.z; xl[(t4 << 2) + 3][c] = v.w;
    }
    __syncthreads();
    const int w = tid >> 6, lane = tid & 63;
    const int row0 = b * NT + t0;
    const uint2* cp = (const uint2*)cand;
    for (int rr = 0; rr < 4; ++rr) {
        const int tl = w * 4 + rr;
        const int row = row0 + tl;
        float4 xa = *(const float4*)&xl[tl][lane << 3];
        float4 xb = *(const float4*)&xl[tl][(lane << 3) + 4];
        int n = (int)candcnt[row]; if (n > CAP) n = CAP;
        uint2 pr = make_uint2(0x7FFFFFFFu, 0x7F800000u);   // (code=max, score=+inf)
        if (lane < n) pr = cp[(size_t)row * CAP + lane];
        float scf = __uint_as_float(pr.y);
        float rmin = scf;
        #pragma unroll
        for (int off = 1; off < 64; off <<= 1) rmin = fminf(rmin, __shfl_xor(rmin, off, 64));
        unsigned long long msk = __ballot(scf <= rmin + DELTA);
        float bs = 3.402823466e38f; int bi = 0x7FFFFFFF;
        while (msk) {
            int j = (int)__ffsll(msk) - 1; msk &= msk - 1;
            int code = __shfl((int)pr.x, j, 64);
            const float* cr = cb + (size_t)code * NC + (lane << 3);
            float4 ca = *(const float4*)cr;
            float4 cc = *(const float4*)(cr + 4);
            float s = xa.x*ca.x + xa.y*ca.y + xa.z*ca.z + xa.w*ca.w
                    + xb.x*cc.x + xb.y*cc.y + xb.z*cc.z + xb.w*cc.w;
            #pragma unroll
            for (int off = 1; off < 64; off <<= 1) s += __shfl_xor(s, off, 64);
            s = cbn[code] - s;
            if (s < bs || (s == bs && code < bi)) { bs = s; bi = code; }
        }
        if (lane == 0) {
            best_idx[row] = bi;
            out_idx[(size_t)row * NQ + q] = (float)bi;
            atomicAdd(&counts[bi], 1u);
        }
    }
}

// -------- gather + residual update + commit + bf16 emit + FUSED stats --------
// grid 256 blocks (64 rows each), 256 threads; last block computes perp/cmean.
// xh emission is panel-major swizzled (matches vq_dist staging layout).
__global__ __launch_bounds__(256) void vq_update(
    const float* __restrict__ src,    // residual before (x for q=0), (B,C,T)
    float* __restrict__ dst,          // residual after (d_out qout slot)
    const float* __restrict__ cb,
    const int* __restrict__ best_idx,
    unsigned short* __restrict__ xh,  // bf16 residual for next layer's dist
    unsigned int* __restrict__ candcnt,
    unsigned int* __restrict__ counts,
    float* __restrict__ csum, float* __restrict__ cmean, float* __restrict__ perp,
    float* __restrict__ out_tail, unsigned int* __restrict__ done, int q)
{
    const int rb = blockIdx.x, tid = threadIdx.x;
    const int b = rb >> 2, t0 = (rb & 3) << 6;
    const int row0 = rb * 64;                    // = b*256 + t0
    __shared__ int s_idx[64];
    __shared__ __align__(16) float qt[64][68];   // [c_local][t_local]
    __shared__ float wsum[4];
    __shared__ unsigned int lastflag;
    if (tid < 64) {
        s_idx[tid] = best_idx[row0 + tid];
        candcnt[row0 + tid] = 0u;                // reset for next layer's dist
    }
    __syncthreads();
    float cs = 0.f;
    const size_t base = (size_t)b * (NC * NT) + t0;
    for (int ct = 0; ct < 8; ++ct) {             // c chunks of 64 (= panel kk)
        if (ct) __syncthreads();
        // gather cb[idx[r]] chunk into qt [c][t]
        #pragma unroll
        for (int i = 0; i < 4; ++i) {
            int f = tid + (i << 8);
            int r = f >> 4, cf = f & 15;
            float4 v = *(const float4*)(cb + (size_t)s_idx[r] * NC + ct * 64 + (cf << 2));
            qt[(cf << 2) + 0][r] = v.x;
            qt[(cf << 2) + 1][r] = v.y;
            qt[(cf << 2) + 2][r] = v.z;
            qt[(cf << 2) + 3][r] = v.w;
        }
        __syncthreads();
        // residual RMW (coalesced along t); overwrite qt cells with n in place
        #pragma unroll
        for (int i = 0; i < 4; ++i) {
            int f = tid + (i << 8);
            int c_l = f >> 4, tf = f & 15;
            size_t o = base + (size_t)(ct * 64 + c_l) * NT + (tf << 2);
            float4 r4 = *(const float4*)(src + o);
            float4 q4 = *(const float4*)&qt[c_l][tf << 2];
            float4 n;
            n.x = r4.x - q4.x; n.y = r4.y - q4.y; n.z = r4.z - q4.z; n.w = r4.w - q4.w;
            *(float4*)(dst + o) = n;
            *(float4*)&qt[c_l][tf << 2] = n;
            cs += n.x*n.x + n.y*n.y + n.z*n.z + n.w*n.w;
        }
        __syncthreads();
        // transpose-read n and emit bf16 panel-major swizzled
        #pragma unroll
        for (int i = 0; i < 4; ++i) {
            int f = tid + (i << 8);
            int r_l = f >> 4, c4 = f & 15;
            ushort4 hh;
            hh.x = f2bf(qt[c4*4+0][r_l]); hh.y = f2bf(qt[c4*4+1][r_l]);
            hh.z = f2bf(qt[c4*4+2][r_l]); hh.w = f2bf(qt[c4*4+3][r_l]);
            int cq = c4 >> 1, h = c4 & 1;
            *(ushort4*)(xh + (((size_t)ct * NROWS + row0 + r_l) << 6)
                           + ((cq ^ (r_l & 7)) << 3) + (h << 2)) = hh;
        }
    }
    #pragma unroll
    for (int off = 32; off; off >>= 1) cs += __shfl_down(cs, off, 64);
    if ((tid & 63) == 0) wsum[tid >> 6] = cs;
    __syncthreads();
    if (tid == 0) {
        atomicAdd(&csum[q], wsum[0] + wsum[1] + wsum[2] + wsum[3]);
        __threadfence();
        lastflag = atomicAdd(done, 1u);
    }
    __syncthreads();
    if (lastflag == 255u) {                      // last block: fused per-layer stats
        float v = 0.f;
        for (int i = tid; i < NK; i += 256) {
            float p = (float)atomicAdd(&counts[i], 0u) * (1.f / (float)NROWS);
            v += p * logf(p + 1e-7f);
        }
        #pragma unroll
        for (int off = 32; off; off >>= 1) v += __shfl_down(v, off, 64);
        if ((tid & 63) == 0) wsum[tid >> 6] = v;
        __syncthreads();
        if (tid == 0) {
            float S = wsum[0] + wsum[1] + wsum[2] + wsum[3];
            perp[q]  = expf(-S);
            cmean[q] = atomicAdd(&csum[q], 0.f) * (1.f / ((float)NROWS * (float)NC));
            if (q == NQ - 1) {
                float mc = 0.f, mp = 0.f;
                for (int i = 0; i < NQ; ++i) { mc += cmean[i]; mp += perp[i]; }
                out_tail[0] = mc / (float)NQ;
                out_tail[1] = mp / (float)NQ;
            }
            *done = 0u;                          // reset for next layer
        }
    }
}

// -------- qout = x - residual_final (elementwise, in place) --------
__global__ void vq_finalize(const float* __restrict__ x, float* __restrict__ res, int n4) {
    int i = blockIdx.x * blockDim.x + threadIdx.x;
    if (i < n4) {
        float4 a = ((const float4*)x)[i];
        float4 r = ((float4*)res)[i];
        float4 o;
        o.x = a.x - r.x; o.y = a.y - r.y; o.z = a.z - r.z; o.w = a.w - r.w;
        ((float4*)res)[i] = o;
    }
}

extern "C" void kernel_launch(void* const* d_in, const int* in_sizes, int n_in,
                              void* d_out, int out_size, void* d_ws, size_t ws_size,
                              hipStream_t stream) {
    static int inited = 0;
    if (!inited) {
        // allow 128 KiB dynamic LDS for vq_dist (gfx950 has 160 KiB/CU)
        (void)hipFuncSetAttribute((const void*)vq_dist,
                                  hipFuncAttributeMaxDynamicSharedMemorySize, 131072);
        inited = 1;
    }
    const float* x  = (const float*)d_in[0];
    const float* cb = (const float*)d_in[1];       // (Q,K,C)
    float* out      = (float*)d_out;
    float* res      = out;                          // residual lives in qout slot
    float* out_idx  = out + QOUT_ELEMS;
    float* out_tail = out + QOUT_ELEMS + IDX_ELEMS;
    char* ws = (char*)d_ws;
    unsigned int* cand    = (unsigned int*)(ws + WS_CAND);
    unsigned int* candcnt = (unsigned int*)(ws + WS_CCNT);
    int*          bidx    = (int*)(ws + WS_BIDX);
    unsigned int* counts  = (unsigned int*)(ws + WS_COUNTS);
    float* csum  = (float*)(ws + WS_CSUM);
    float* cmean = (float*)(ws + WS_CMEAN);
    float* perp  = (float*)(ws + WS_PERP);
    unsigned int* done = (unsigned int*)(ws + WS_DONE);
    float* cbn   = (float*)(ws + WS_CBN);
    unsigned short* xh   = (unsigned short*)(ws + WS_XHI);
    unsigned short* cbhi = (unsigned short*)(ws + WS_CBHI);

    vq_cvt_cb<<<1536, 256, 0, stream>>>(cb, cbhi, cbn);
    vq_cvt_x<<<2048, 256, 0, stream>>>(x, xh, candcnt, done);
    for (int q = 0; q < NQ; ++q) {
        const float* src = (q == 0) ? x : res;
        const float* cbq = cb + (size_t)q * NK * NC;
        vq_dist<<<dim3(64, 4), 512, 131072, stream>>>(
            xh, cbhi + (size_t)q * NK * NC, cbn + q * NK,
            cand, candcnt, counts, csum + q);
        vq_rescore<<<1024, 256, 0, stream>>>(src, cbq, cbn + q * NK, cand, candcnt,
                                             bidx, out_idx, counts, q);
        vq_update<<<256, 256, 0, stream>>>(src, res, cbq, bidx, xh, candcnt,
                                           counts, csum, cmean, perp, out_tail, done, q);
    }
    vq_finalize<<<8192, 256, 0, stream>>>(x, res, QOUT_ELEMS / 4);
}